// Round 1
// baseline (934.632 us; speedup 1.0000x reference)
//
#include <hip/hip_runtime.h>
#include <hip/hip_bf16.h>
#include <math.h>

// ---------------------------------------------------------------------------
// Types
// ---------------------------------------------------------------------------
typedef short v8s __attribute__((ext_vector_type(8)));   // 8 x bf16 bits (4 VGPR)
typedef float v4f __attribute__((ext_vector_type(4)));   // MFMA accumulator

__device__ __forceinline__ unsigned short f2bf(float f) {
  union { float f; unsigned u; } a; a.f = f;
  unsigned u = a.u + 0x7fffu + ((a.u >> 16) & 1u);   // RNE
  return (unsigned short)(u >> 16);
}

// ---------------------------------------------------------------------------
// fp32 -> bf16 (same layout), vectorized x4
// ---------------------------------------------------------------------------
__global__ void cvt_f32_bf16(const float* __restrict__ in,
                             unsigned short* __restrict__ out, int n4) {
  int i = blockIdx.x * blockDim.x + threadIdx.x;
  if (i >= n4) return;
  float4 v = reinterpret_cast<const float4*>(in)[i];
  ushort4 o;
  o.x = f2bf(v.x); o.y = f2bf(v.y); o.z = f2bf(v.z); o.w = f2bf(v.w);
  reinterpret_cast<ushort4*>(out)[i] = o;
}

// ---------------------------------------------------------------------------
// fp32 [K,N] -> bf16 [N,K] transpose-convert (weights). block (32,8)
// ---------------------------------------------------------------------------
__global__ void cvt_transpose(const float* __restrict__ in,
                              unsigned short* __restrict__ out, int K, int N) {
  __shared__ float t[32][33];
  int bx = blockIdx.x, by = blockIdx.y;
  int tx = threadIdx.x, ty = threadIdx.y;
#pragma unroll
  for (int i = 0; i < 4; i++) {
    int k = by * 32 + ty + i * 8;
    t[ty + i * 8][tx] = in[(size_t)k * N + bx * 32 + tx];
  }
  __syncthreads();
#pragma unroll
  for (int i = 0; i < 4; i++) {
    int n = bx * 32 + ty + i * 8;
    out[(size_t)n * K + by * 32 + tx] = f2bf(t[tx][ty + i * 8]);
  }
}

// ---------------------------------------------------------------------------
// bf16 MFMA GEMM: C[M,N] = act(A[M,K] @ B[K,N] + bias)
// A row-major bf16, BT = B^T row-major [N,K] bf16.
// 256 threads = 4 waves, tile 128x128, BK=32, each wave 64x64 (4x4 MFMA tiles).
// Handles ragged M (guarded loads/stores); N,K must be multiples of 128/32.
// ---------------------------------------------------------------------------
template<bool RELU, bool OUTF, bool OUTB>
__global__ __launch_bounds__(256)
void gemm_bf16(const unsigned short* __restrict__ A,
               const unsigned short* __restrict__ BT,
               const float* __restrict__ bias,
               float* __restrict__ Cf, unsigned short* __restrict__ Cb,
               int M, int N, int K) {
  // +8 shorts pad: row stride 80B -> frag reads ~2-way bank alias (free)
  __shared__ __align__(16) unsigned short lA[128][40];
  __shared__ __align__(16) unsigned short lB[128][40];
  int tid  = threadIdx.x;
  int lane = tid & 63;
  int wave = tid >> 6;
  int wr = (wave >> 1) * 64;
  int wc = (wave & 1) * 64;
  int quad = lane >> 4;
  int l15  = lane & 15;
  int m0 = blockIdx.y * 128;
  int n0 = blockIdx.x * 128;
  int sr = tid >> 1;            // 0..127
  int sc = (tid & 1) * 16;      // 0 or 16

  const v4f vzero = {0.f, 0.f, 0.f, 0.f};
  v4f acc[4][4];
#pragma unroll
  for (int i = 0; i < 4; i++)
#pragma unroll
    for (int j = 0; j < 4; j++) acc[i][j] = vzero;

  const unsigned short* Arow = A  + (size_t)(m0 + sr) * K + sc;
  const unsigned short* Brow = BT + (size_t)(n0 + sr) * K + sc;
  bool aok = (m0 + sr) < M;

  for (int k0 = 0; k0 < K; k0 += 32) {
    v8s a0 = {}, a1 = {};
    if (aok) {
      a0 = *(const v8s*)(Arow + k0);
      a1 = *(const v8s*)(Arow + k0 + 8);
    }
    v8s b0 = *(const v8s*)(Brow + k0);
    v8s b1 = *(const v8s*)(Brow + k0 + 8);
    __syncthreads();                       // prev iter frag reads done
    *(v8s*)&lA[sr][sc]     = a0;
    *(v8s*)&lA[sr][sc + 8] = a1;
    *(v8s*)&lB[sr][sc]     = b0;
    *(v8s*)&lB[sr][sc + 8] = b1;
    __syncthreads();
    v8s aF[4], bF[4];
#pragma unroll
    for (int i = 0; i < 4; i++) aF[i] = *(const v8s*)&lA[wr + i * 16 + l15][quad * 8];
#pragma unroll
    for (int j = 0; j < 4; j++) bF[j] = *(const v8s*)&lB[wc + j * 16 + l15][quad * 8];
#pragma unroll
    for (int i = 0; i < 4; i++)
#pragma unroll
      for (int j = 0; j < 4; j++)
        acc[i][j] = __builtin_amdgcn_mfma_f32_16x16x32_bf16(aF[i], bF[j], acc[i][j], 0, 0, 0);
  }

  // epilogue: C/D layout col=lane&15, row=quad*4+reg
#pragma unroll
  for (int j = 0; j < 4; j++) {
    int col = n0 + wc + j * 16 + l15;
    float bv = bias ? bias[col] : 0.f;
#pragma unroll
    for (int i = 0; i < 4; i++) {
#pragma unroll
      for (int r = 0; r < 4; r++) {
        int row = m0 + wr + i * 16 + quad * 4 + r;
        if (row < M) {
          float v = acc[i][j][r] + bv;
          if (RELU) v = fmaxf(v, 0.f);
          if (OUTF) Cf[(size_t)row * N + col] = v;
          if (OUTB) Cb[(size_t)row * N + col] = f2bf(v);
        }
      }
    }
  }
}

// ---------------------------------------------------------------------------
// Flash-style MFMA attention. grid (Sq/64, H, B), 256 threads = 4 waves.
// One WG: 64 query rows of one (b,h); KV chunks of 64, online softmax.
// Q/K/V bf16 with row stride; O bf16 [B*Sq, H*64] head-merged.
// ---------------------------------------------------------------------------
__global__ __launch_bounds__(256)
void attn_kernel(const unsigned short* __restrict__ Q,
                 const unsigned short* __restrict__ K,
                 const unsigned short* __restrict__ V,
                 unsigned short* __restrict__ O,
                 int q_rowstride, int kv_rowstride, int o_rowstride,
                 int q_batch_rows, int kv_batch_rows, int Skv, float scale) {
  __shared__ __align__(16) unsigned short lK[64][72];      // [kv][d]
  __shared__ __align__(16) unsigned short lV[64][72];      // transposed: [d][kv]
  __shared__ __align__(16) unsigned short lP[4][16][72];   // per-wave P (A-layout src)
  int tid  = threadIdx.x;
  int lane = tid & 63;
  int wave = tid >> 6;
  int quad = lane >> 4;
  int l15  = lane & 15;
  int qt = blockIdx.x, h = blockIdx.y, b = blockIdx.z;

  const unsigned short* Qb = Q + (size_t)b * q_batch_rows * q_rowstride + h * 64;
  const unsigned short* Kb = K + (size_t)b * kv_batch_rows * kv_rowstride + h * 64;
  const unsigned short* Vb = V + (size_t)b * kv_batch_rows * kv_rowstride + h * 64;

  // Q A-frags (rows qt*64 + wave*16 + l15, k = c*32 + quad*8 + j)
  v8s qf0, qf1;
  {
    const unsigned short* qr = Qb + (size_t)(qt * 64 + wave * 16 + l15) * q_rowstride + quad * 8;
    qf0 = *(const v8s*)(qr);
    qf1 = *(const v8s*)(qr + 32);
  }

  const v4f vzero = {0.f, 0.f, 0.f, 0.f};
  v4f o_acc[4];
#pragma unroll
  for (int t = 0; t < 4; t++) o_acc[t] = vzero;
  float m_r[4], l_r[4];
#pragma unroll
  for (int r = 0; r < 4; r++) { m_r[r] = -1e30f; l_r[r] = 0.f; }

  int sr = tid >> 2;            // kv row in chunk 0..63
  int sc = (tid & 3) * 16;      // 0/16/32/48

  int nch = (Skv + 63) >> 6;
  for (int ch = 0; ch < nch; ch++) {
    int base = ch * 64;
    int gr = base + sr;
    v8s k0v = {}, k1v = {}, v0v = {}, v1v = {};
    if (gr < Skv) {
      const unsigned short* kp = Kb + (size_t)gr * kv_rowstride + sc;
      const unsigned short* vp = Vb + (size_t)gr * kv_rowstride + sc;
      k0v = *(const v8s*)kp;  k1v = *(const v8s*)(kp + 8);
      v0v = *(const v8s*)vp;  v1v = *(const v8s*)(vp + 8);
    }
    __syncthreads();            // prev chunk's lV/lP reads done
    *(v8s*)&lK[sr][sc]     = k0v;
    *(v8s*)&lK[sr][sc + 8] = k1v;
#pragma unroll
    for (int e = 0; e < 8; e++) {
      lV[sc + e][sr]     = (unsigned short)v0v[e];
      lV[sc + 8 + e][sr] = (unsigned short)v1v[e];
    }
    __syncthreads();

    // S = Q K^T for 4 kv sub-tiles of 16
    float s[4][4];
#pragma unroll
    for (int t = 0; t < 4; t++) {
      v8s kf0 = *(const v8s*)&lK[t * 16 + l15][quad * 8];
      v8s kf1 = *(const v8s*)&lK[t * 16 + l15][32 + quad * 8];
      v4f sacc = vzero;
      sacc = __builtin_amdgcn_mfma_f32_16x16x32_bf16(qf0, kf0, sacc, 0, 0, 0);
      sacc = __builtin_amdgcn_mfma_f32_16x16x32_bf16(qf1, kf1, sacc, 0, 0, 0);
      int kvpos = base + t * 16 + l15;     // C-layout col = lane&15
      bool ok = kvpos < Skv;
#pragma unroll
      for (int r = 0; r < 4; r++) s[t][r] = ok ? sacc[r] * scale : -1e30f;
    }

    // online softmax per row (row r lives in the 16 lanes of this quad)
#pragma unroll
    for (int r = 0; r < 4; r++) {
      float mx = fmaxf(fmaxf(s[0][r], s[1][r]), fmaxf(s[2][r], s[3][r]));
#pragma unroll
      for (int d = 1; d < 16; d <<= 1) mx = fmaxf(mx, __shfl_xor(mx, d));
      float mnew = fmaxf(m_r[r], mx);
      float alpha = __expf(m_r[r] - mnew);
      float sm = 0.f;
#pragma unroll
      for (int t = 0; t < 4; t++) { s[t][r] = __expf(s[t][r] - mnew); sm += s[t][r]; }
#pragma unroll
      for (int d = 1; d < 16; d <<= 1) sm += __shfl_xor(sm, d);
      l_r[r] = l_r[r] * alpha + sm;
      m_r[r] = mnew;
#pragma unroll
      for (int t = 0; t < 4; t++) o_acc[t][r] *= alpha;
    }

    // P: C-layout -> LDS -> A-layout
#pragma unroll
    for (int t = 0; t < 4; t++)
#pragma unroll
      for (int r = 0; r < 4; r++)
        lP[wave][quad * 4 + r][t * 16 + l15] = f2bf(s[t][r]);
    __syncthreads();
    v8s pf0 = *(const v8s*)&lP[wave][l15][quad * 8];
    v8s pf1 = *(const v8s*)&lP[wave][l15][32 + quad * 8];
#pragma unroll
    for (int t = 0; t < 4; t++) {
      v8s vf0 = *(const v8s*)&lV[t * 16 + l15][quad * 8];
      v8s vf1 = *(const v8s*)&lV[t * 16 + l15][32 + quad * 8];
      o_acc[t] = __builtin_amdgcn_mfma_f32_16x16x32_bf16(pf0, vf0, o_acc[t], 0, 0, 0);
      o_acc[t] = __builtin_amdgcn_mfma_f32_16x16x32_bf16(pf1, vf1, o_acc[t], 0, 0, 0);
    }
  }

  // epilogue: O /= l, write bf16 head-merged
  int orow0 = b * q_batch_rows + qt * 64 + wave * 16;
#pragma unroll
  for (int t = 0; t < 4; t++) {
#pragma unroll
    for (int r = 0; r < 4; r++) {
      float v = o_acc[t][r] / l_r[r];
      O[(size_t)(orow0 + quad * 4 + r) * o_rowstride + h * 64 + t * 16 + l15] = f2bf(v);
    }
  }
}

// ---------------------------------------------------------------------------
// Fused residual + LayerNorm over D=1024. 256 threads, 4 cols/thread.
// out_f32 may alias base (in-place safe: each thread only rewrites what it read)
// ---------------------------------------------------------------------------
__global__ __launch_bounds__(256)
void ln_kernel(const float* base, const float* __restrict__ delta,
               const float* __restrict__ g, const float* __restrict__ bb,
               float* outf, unsigned short* __restrict__ outb) {
  __shared__ float red[8];
  int row = blockIdx.x;
  int tid = threadIdx.x;
  float4 vb = ((const float4*)(base  + (size_t)row * 1024))[tid];
  float4 vd = ((const float4*)(delta + (size_t)row * 1024))[tid];
  float v0 = vb.x + vd.x, v1 = vb.y + vd.y, v2 = vb.z + vd.z, v3 = vb.w + vd.w;
  float s = v0 + v1 + v2 + v3;
  float q = v0 * v0 + v1 * v1 + v2 * v2 + v3 * v3;
#pragma unroll
  for (int d = 1; d < 64; d <<= 1) { s += __shfl_xor(s, d); q += __shfl_xor(q, d); }
  int wave = tid >> 6, lane = tid & 63;
  if (lane == 0) { red[wave] = s; red[4 + wave] = q; }
  __syncthreads();
  s = red[0] + red[1] + red[2] + red[3];
  q = red[4] + red[5] + red[6] + red[7];
  float mean = s * (1.f / 1024.f);
  float var  = q * (1.f / 1024.f) - mean * mean;
  float rstd = rsqrtf(var + 1e-5f);
  float4 gg  = ((const float4*)g)[tid];
  float4 bv  = ((const float4*)bb)[tid];
  float o0 = (v0 - mean) * rstd * gg.x + bv.x;
  float o1 = (v1 - mean) * rstd * gg.y + bv.y;
  float o2 = (v2 - mean) * rstd * gg.z + bv.z;
  float o3 = (v3 - mean) * rstd * gg.w + bv.w;
  if (outf) {
    float4 o; o.x = o0; o.y = o1; o.z = o2; o.w = o3;
    ((float4*)(outf + (size_t)row * 1024))[tid] = o;
  }
  if (outb) {
    ushort4 u; u.x = f2bf(o0); u.y = f2bf(o1); u.z = f2bf(o2); u.w = f2bf(o3);
    ((ushort4*)(outb + (size_t)row * 1024))[tid] = u;
  }
}

// ---------------------------------------------------------------------------
// Launch
// ---------------------------------------------------------------------------
extern "C" void kernel_launch(void* const* d_in, const int* in_sizes, int n_in,
                              void* d_out, int out_size, void* d_ws, size_t ws_size,
                              hipStream_t stream) {
  const float* x     = (const float*)d_in[0];
  const float* y     = (const float*)d_in[1];
  const float* w_qkv = (const float*)d_in[2];
  const float* b_qkv = (const float*)d_in[3];
  const float* w_so  = (const float*)d_in[4];
  const float* b_so  = (const float*)d_in[5];
  const float* w_q   = (const float*)d_in[6];
  const float* b_q   = (const float*)d_in[7];
  const float* w_k   = (const float*)d_in[8];
  const float* b_k   = (const float*)d_in[9];
  const float* w_v   = (const float*)d_in[10];
  const float* b_v   = (const float*)d_in[11];
  const float* w_co  = (const float*)d_in[12];
  const float* b_co  = (const float*)d_in[13];
  const float* w1    = (const float*)d_in[14];
  const float* b1    = (const float*)d_in[15];
  const float* w2    = (const float*)d_in[16];
  const float* b2    = (const float*)d_in[17];
  const float* w3    = (const float*)d_in[18];
  const float* b3    = (const float*)d_in[19];
  const float* ln_g  = (const float*)d_in[20];
  const float* ln_b  = (const float*)d_in[21];

  char* ws = (char*)d_ws;
  auto US = [&](size_t off) { return (unsigned short*)(ws + off); };
  auto FP = [&](size_t off) { return (float*)(ws + off); };

  // ws layout (bytes). Total 175,585,280 (~168 MB).
  constexpr size_t o_wqkv = 0;                                 // [3072,1024] bf16
  constexpr size_t o_wso  = o_wqkv + 3072ull * 1024 * 2;       // [1024,1024]
  constexpr size_t o_wq   = o_wso  + 1024ull * 1024 * 2;
  constexpr size_t o_wk   = o_wq   + 1024ull * 1024 * 2;       // [1024,768]
  constexpr size_t o_wv   = o_wk   + 1024ull * 768 * 2;
  constexpr size_t o_wco  = o_wv   + 1024ull * 768 * 2;
  constexpr size_t o_w1   = o_wco  + 1024ull * 1024 * 2;       // [4096,1024]
  constexpr size_t o_w2   = o_w1   + 4096ull * 1024 * 2;       // [4096,4096]
  constexpr size_t o_w3   = o_w2   + 4096ull * 4096 * 2;       // [1024,4096]
  constexpr size_t o_xf   = o_w3   + 1024ull * 4096 * 2;       // x fp32 [4096,1024]
  constexpr size_t o_xbf  = o_xf   + 4096ull * 1024 * 4;       // x bf16
  constexpr size_t o_ybf  = o_xbf  + 4096ull * 1024 * 2;       // y bf16 [308,768]
  constexpr size_t o_dlt  = o_ybf  + 308ull * 768 * 2;         // delta fp32 [4096,1024]
  constexpr size_t o_R1   = o_dlt  + 4096ull * 1024 * 4;       // qkv bf16 [4096,3072]
  constexpr size_t o_attn = o_R1   + 4096ull * 3072 * 2;       // attn out bf16 [4096,1024]
  constexpr size_t o_R2   = o_attn + 4096ull * 1024 * 2;       // h2 bf16 [4096,4096]
  // aliases (liveness-checked): qc/kc/vc overlay dead qkv; h1 overlays qkv+attn
  constexpr size_t o_qc = o_R1;
  constexpr size_t o_kc = o_R1 + 4096ull * 1024 * 2;
  constexpr size_t o_vc = o_kc + 308ull * 1024 * 2;
  constexpr size_t o_h1 = o_R1;                                // 33,554,432 B span
  constexpr size_t o_h2 = o_R2;

  dim3 tb(32, 8);
  // weight transpose-converts: in [K,N] fp32 -> out [N,K] bf16, grid (N/32,K/32)
  cvt_transpose<<<dim3(96, 32),  tb, 0, stream>>>(w_qkv, US(o_wqkv), 1024, 3072);
  cvt_transpose<<<dim3(32, 32),  tb, 0, stream>>>(w_so,  US(o_wso),  1024, 1024);
  cvt_transpose<<<dim3(32, 32),  tb, 0, stream>>>(w_q,   US(o_wq),   1024, 1024);
  cvt_transpose<<<dim3(32, 24),  tb, 0, stream>>>(w_k,   US(o_wk),   768,  1024);
  cvt_transpose<<<dim3(32, 24),  tb, 0, stream>>>(w_v,   US(o_wv),   768,  1024);
  cvt_transpose<<<dim3(32, 32),  tb, 0, stream>>>(w_co,  US(o_wco),  1024, 1024);
  cvt_transpose<<<dim3(128, 32), tb, 0, stream>>>(w1,    US(o_w1),   1024, 4096);
  cvt_transpose<<<dim3(128, 128),tb, 0, stream>>>(w2,    US(o_w2),   4096, 4096);
  cvt_transpose<<<dim3(32, 128), tb, 0, stream>>>(w3,    US(o_w3),   4096, 1024);

  cvt_f32_bf16<<<4096, 256, 0, stream>>>(x, US(o_xbf), 4096 * 1024 / 4);
  cvt_f32_bf16<<<231, 256, 0, stream>>>(y, US(o_ybf), 4 * 77 * 768 / 4);

  // --- self attention ---
  gemm_bf16<false, false, true><<<dim3(24, 32), 256, 0, stream>>>(
      US(o_xbf), US(o_wqkv), b_qkv, nullptr, US(o_R1), 4096, 3072, 1024);
  attn_kernel<<<dim3(16, 16, 4), 256, 0, stream>>>(
      US(o_R1), US(o_R1) + 1024, US(o_R1) + 2048, US(o_attn),
      3072, 3072, 1024, 1024, 1024, 1024, 0.125f);
  gemm_bf16<false, true, false><<<dim3(8, 32), 256, 0, stream>>>(
      US(o_attn), US(o_wso), b_so, FP(o_dlt), nullptr, 4096, 1024, 1024);
  ln_kernel<<<4096, 256, 0, stream>>>(x, FP(o_dlt), ln_g, ln_b, FP(o_xf), US(o_xbf));

  // --- cross attention ---
  gemm_bf16<false, false, true><<<dim3(8, 32), 256, 0, stream>>>(
      US(o_xbf), US(o_wq), b_q, nullptr, US(o_qc), 4096, 1024, 1024);
  gemm_bf16<false, false, true><<<dim3(8, 3), 256, 0, stream>>>(
      US(o_ybf), US(o_wk), b_k, nullptr, US(o_kc), 308, 1024, 768);
  gemm_bf16<false, false, true><<<dim3(8, 3), 256, 0, stream>>>(
      US(o_ybf), US(o_wv), b_v, nullptr, US(o_vc), 308, 1024, 768);
  attn_kernel<<<dim3(16, 16, 4), 256, 0, stream>>>(
      US(o_qc), US(o_kc), US(o_vc), US(o_attn),
      1024, 1024, 1024, 1024, 77, 77, 0.125f);
  gemm_bf16<false, true, false><<<dim3(8, 32), 256, 0, stream>>>(
      US(o_attn), US(o_wco), b_co, FP(o_dlt), nullptr, 4096, 1024, 1024);
  ln_kernel<<<4096, 256, 0, stream>>>(FP(o_xf), FP(o_dlt), ln_g, ln_b, FP(o_xf), US(o_xbf));

  // --- FFN ---
  gemm_bf16<true, false, true><<<dim3(32, 32), 256, 0, stream>>>(
      US(o_xbf), US(o_w1), b1, nullptr, US(o_h1), 4096, 4096, 1024);
  gemm_bf16<true, false, true><<<dim3(32, 32), 256, 0, stream>>>(
      US(o_h1), US(o_w2), b2, nullptr, US(o_h2), 4096, 4096, 4096);
  gemm_bf16<false, true, false><<<dim3(8, 32), 256, 0, stream>>>(
      US(o_h2), US(o_w3), b3, FP(o_dlt), nullptr, 4096, 1024, 4096);
  ln_kernel<<<4096, 256, 0, stream>>>(FP(o_xf), FP(o_dlt), ln_g, ln_b, (float*)d_out, nullptr);
}

// Round 2
// 932.374 us; speedup vs baseline: 1.0024x; 1.0024x over previous
//
#include <hip/hip_runtime.h>
#include <hip/hip_bf16.h>
#include <math.h>

// ---------------------------------------------------------------------------
// Types
// ---------------------------------------------------------------------------
typedef short v8s __attribute__((ext_vector_type(8)));   // 8 x bf16 bits (4 VGPR)
typedef float v4f __attribute__((ext_vector_type(4)));   // MFMA accumulator

__device__ __forceinline__ unsigned short f2bf(float f) {
  union { float f; unsigned u; } a; a.f = f;
  unsigned u = a.u + 0x7fffu + ((a.u >> 16) & 1u);   // RNE
  return (unsigned short)(u >> 16);
}

// async global->LDS, 16 B per lane; LDS dest = wave-uniform base + lane*16
__device__ __forceinline__ void gld_lds16(const unsigned short* g, unsigned short* l) {
  __builtin_amdgcn_global_load_lds(
      (const __attribute__((address_space(1))) void*)g,
      (__attribute__((address_space(3))) void*)l,
      16, 0, 0);
}

// ---------------------------------------------------------------------------
// fp32 -> bf16 (same layout), vectorized x4
// ---------------------------------------------------------------------------
__global__ void cvt_f32_bf16(const float* __restrict__ in,
                             unsigned short* __restrict__ out, int n4) {
  int i = blockIdx.x * blockDim.x + threadIdx.x;
  if (i >= n4) return;
  float4 v = reinterpret_cast<const float4*>(in)[i];
  ushort4 o;
  o.x = f2bf(v.x); o.y = f2bf(v.y); o.z = f2bf(v.z); o.w = f2bf(v.w);
  reinterpret_cast<ushort4*>(out)[i] = o;
}

// ---------------------------------------------------------------------------
// fp32 [K,N] -> bf16 [N,K] transpose-convert (weights). block (32,8)
// ---------------------------------------------------------------------------
__global__ void cvt_transpose(const float* __restrict__ in,
                              unsigned short* __restrict__ out, int K, int N) {
  __shared__ float t[32][33];
  int bx = blockIdx.x, by = blockIdx.y;
  int tx = threadIdx.x, ty = threadIdx.y;
#pragma unroll
  for (int i = 0; i < 4; i++) {
    int k = by * 32 + ty + i * 8;
    t[ty + i * 8][tx] = in[(size_t)k * N + bx * 32 + tx];
  }
  __syncthreads();
#pragma unroll
  for (int i = 0; i < 4; i++) {
    int n = bx * 32 + ty + i * 8;
    out[(size_t)n * K + by * 32 + tx] = f2bf(t[tx][ty + i * 8]);
  }
}

// ---------------------------------------------------------------------------
// bf16 MFMA GEMM (m97 structure): C[M,N] = act(A[M,K] @ B[K,N] + bias)
// A row-major bf16, BT = B^T row-major [N,K] bf16.
// 256 threads = 4 waves, tile 128x128, BK=32, each wave 64x64 (4x4 MFMA tiles).
// Staging via global_load_lds width=16 into UNPADDED lA/lB [128][32]
// (wave-uniform LDS base + lane*16 constraint forbids padding).
// Per K-step: 4 async issues/thread, 2 barriers, 8 ds_read_b128, 16 MFMA.
// Ragged M: OOB rows read workspace garbage (mapped) and are discarded at store.
// N,K must be multiples of 128/32.
// ---------------------------------------------------------------------------
template<bool RELU, bool OUTF, bool OUTB>
__global__ __launch_bounds__(256)
void gemm_bf16(const unsigned short* __restrict__ A,
               const unsigned short* __restrict__ BT,
               const float* __restrict__ bias,
               float* __restrict__ Cf, unsigned short* __restrict__ Cb,
               int M, int N, int K) {
  __shared__ __align__(16) unsigned short lA[128 * 32];   // 8 KB, unpadded
  __shared__ __align__(16) unsigned short lB[128 * 32];
  int tid  = threadIdx.x;
  int lane = tid & 63;
  int wave = tid >> 6;
  int wr = (wave >> 1) * 64;
  int wc = (wave & 1) * 64;
  int quad = lane >> 4;
  int l15  = lane & 15;
  int m0 = blockIdx.y * 128;
  int n0 = blockIdx.x * 128;

  // staging map: byte off in tile = wave*1024 + lane*16  ->  row=tid>>2, chunk=(tid&3)
  int srow = tid >> 2;           // 0..63
  int scol = (tid & 3) * 8;      // shorts (16 B chunks)
  const unsigned short* gA = A  + (size_t)(m0 + srow) * K + scol;
  const unsigned short* gB = BT + (size_t)(n0 + srow) * K + scol;
  unsigned short* ldsA = lA + wave * 512;   // wave-uniform, bytes = wave*1024
  unsigned short* ldsB = lB + wave * 512;
  const size_t half = (size_t)64 * K;       // rows 64..127 of the tile

  const v4f vzero = {0.f, 0.f, 0.f, 0.f};
  v4f acc[4][4];
#pragma unroll
  for (int i = 0; i < 4; i++)
#pragma unroll
    for (int j = 0; j < 4; j++) acc[i][j] = vzero;

  for (int k0 = 0; k0 < K; k0 += 32) {
    gld_lds16(gA + k0,        ldsA);
    gld_lds16(gA + k0 + half, ldsA + 2048);
    gld_lds16(gB + k0,        ldsB);
    gld_lds16(gB + k0 + half, ldsB + 2048);
    __syncthreads();                       // drains vmcnt -> LDS tile ready
    v8s aF[4], bF[4];
#pragma unroll
    for (int i = 0; i < 4; i++) aF[i] = *(const v8s*)&lA[(wr + i * 16 + l15) * 32 + quad * 8];
#pragma unroll
    for (int j = 0; j < 4; j++) bF[j] = *(const v8s*)&lB[(wc + j * 16 + l15) * 32 + quad * 8];
#pragma unroll
    for (int i = 0; i < 4; i++)
#pragma unroll
      for (int j = 0; j < 4; j++)
        acc[i][j] = __builtin_amdgcn_mfma_f32_16x16x32_bf16(aF[i], bF[j], acc[i][j], 0, 0, 0);
    __syncthreads();                       // frag reads done before next overwrite
  }

  // epilogue: C/D layout col=lane&15, row=quad*4+reg
#pragma unroll
  for (int j = 0; j < 4; j++) {
    int col = n0 + wc + j * 16 + l15;
    float bv = bias ? bias[col] : 0.f;
#pragma unroll
    for (int i = 0; i < 4; i++) {
#pragma unroll
      for (int r = 0; r < 4; r++) {
        int row = m0 + wr + i * 16 + quad * 4 + r;
        if (row < M) {
          float v = acc[i][j][r] + bv;
          if (RELU) v = fmaxf(v, 0.f);
          if (OUTF) Cf[(size_t)row * N + col] = v;
          if (OUTB) Cb[(size_t)row * N + col] = f2bf(v);
        }
      }
    }
  }
}

// ---------------------------------------------------------------------------
// Flash-style MFMA attention. grid (Sq/64, H, B), 256 threads = 4 waves.
// One WG: 64 query rows of one (b,h); KV chunks of 64, online softmax.
// Q/K/V bf16 with row stride; O bf16 [B*Sq, H*64] head-merged.
// ---------------------------------------------------------------------------
__global__ __launch_bounds__(256)
void attn_kernel(const unsigned short* __restrict__ Q,
                 const unsigned short* __restrict__ K,
                 const unsigned short* __restrict__ V,
                 unsigned short* __restrict__ O,
                 int q_rowstride, int kv_rowstride, int o_rowstride,
                 int q_batch_rows, int kv_batch_rows, int Skv, float scale) {
  __shared__ __align__(16) unsigned short lK[64][72];      // [kv][d]
  __shared__ __align__(16) unsigned short lV[64][72];      // transposed: [d][kv]
  __shared__ __align__(16) unsigned short lP[4][16][72];   // per-wave P (A-layout src)
  int tid  = threadIdx.x;
  int lane = tid & 63;
  int wave = tid >> 6;
  int quad = lane >> 4;
  int l15  = lane & 15;
  int qt = blockIdx.x, h = blockIdx.y, b = blockIdx.z;

  const unsigned short* Qb = Q + (size_t)b * q_batch_rows * q_rowstride + h * 64;
  const unsigned short* Kb = K + (size_t)b * kv_batch_rows * kv_rowstride + h * 64;
  const unsigned short* Vb = V + (size_t)b * kv_batch_rows * kv_rowstride + h * 64;

  // Q A-frags (rows qt*64 + wave*16 + l15, k = c*32 + quad*8 + j)
  v8s qf0, qf1;
  {
    const unsigned short* qr = Qb + (size_t)(qt * 64 + wave * 16 + l15) * q_rowstride + quad * 8;
    qf0 = *(const v8s*)(qr);
    qf1 = *(const v8s*)(qr + 32);
  }

  const v4f vzero = {0.f, 0.f, 0.f, 0.f};
  v4f o_acc[4];
#pragma unroll
  for (int t = 0; t < 4; t++) o_acc[t] = vzero;
  float m_r[4], l_r[4];
#pragma unroll
  for (int r = 0; r < 4; r++) { m_r[r] = -1e30f; l_r[r] = 0.f; }

  int sr = tid >> 2;            // kv row in chunk 0..63
  int sc = (tid & 3) * 16;      // 0/16/32/48

  int nch = (Skv + 63) >> 6;
  for (int ch = 0; ch < nch; ch++) {
    int base = ch * 64;
    int gr = base + sr;
    v8s k0v = {}, k1v = {}, v0v = {}, v1v = {};
    if (gr < Skv) {
      const unsigned short* kp = Kb + (size_t)gr * kv_rowstride + sc;
      const unsigned short* vp = Vb + (size_t)gr * kv_rowstride + sc;
      k0v = *(const v8s*)kp;  k1v = *(const v8s*)(kp + 8);
      v0v = *(const v8s*)vp;  v1v = *(const v8s*)(vp + 8);
    }
    __syncthreads();            // prev chunk's lV/lP reads done
    *(v8s*)&lK[sr][sc]     = k0v;
    *(v8s*)&lK[sr][sc + 8] = k1v;
#pragma unroll
    for (int e = 0; e < 8; e++) {
      lV[sc + e][sr]     = (unsigned short)v0v[e];
      lV[sc + 8 + e][sr] = (unsigned short)v1v[e];
    }
    __syncthreads();

    // S = Q K^T for 4 kv sub-tiles of 16
    float s[4][4];
#pragma unroll
    for (int t = 0; t < 4; t++) {
      v8s kf0 = *(const v8s*)&lK[t * 16 + l15][quad * 8];
      v8s kf1 = *(const v8s*)&lK[t * 16 + l15][32 + quad * 8];
      v4f sacc = vzero;
      sacc = __builtin_amdgcn_mfma_f32_16x16x32_bf16(qf0, kf0, sacc, 0, 0, 0);
      sacc = __builtin_amdgcn_mfma_f32_16x16x32_bf16(qf1, kf1, sacc, 0, 0, 0);
      int kvpos = base + t * 16 + l15;     // C-layout col = lane&15
      bool ok = kvpos < Skv;
#pragma unroll
      for (int r = 0; r < 4; r++) s[t][r] = ok ? sacc[r] * scale : -1e30f;
    }

    // online softmax per row (row r lives in the 16 lanes of this quad)
#pragma unroll
    for (int r = 0; r < 4; r++) {
      float mx = fmaxf(fmaxf(s[0][r], s[1][r]), fmaxf(s[2][r], s[3][r]));
#pragma unroll
      for (int d = 1; d < 16; d <<= 1) mx = fmaxf(mx, __shfl_xor(mx, d));
      float mnew = fmaxf(m_r[r], mx);
      float alpha = __expf(m_r[r] - mnew);
      float sm = 0.f;
#pragma unroll
      for (int t = 0; t < 4; t++) { s[t][r] = __expf(s[t][r] - mnew); sm += s[t][r]; }
#pragma unroll
      for (int d = 1; d < 16; d <<= 1) sm += __shfl_xor(sm, d);
      l_r[r] = l_r[r] * alpha + sm;
      m_r[r] = mnew;
#pragma unroll
      for (int t = 0; t < 4; t++) o_acc[t][r] *= alpha;
    }

    // P: C-layout -> LDS -> A-layout
#pragma unroll
    for (int t = 0; t < 4; t++)
#pragma unroll
      for (int r = 0; r < 4; r++)
        lP[wave][quad * 4 + r][t * 16 + l15] = f2bf(s[t][r]);
    __syncthreads();
    v8s pf0 = *(const v8s*)&lP[wave][l15][quad * 8];
    v8s pf1 = *(const v8s*)&lP[wave][l15][32 + quad * 8];
#pragma unroll
    for (int t = 0; t < 4; t++) {
      v8s vf0 = *(const v8s*)&lV[t * 16 + l15][quad * 8];
      v8s vf1 = *(const v8s*)&lV[t * 16 + l15][32 + quad * 8];
      o_acc[t] = __builtin_amdgcn_mfma_f32_16x16x32_bf16(pf0, vf0, o_acc[t], 0, 0, 0);
      o_acc[t] = __builtin_amdgcn_mfma_f32_16x16x32_bf16(pf1, vf1, o_acc[t], 0, 0, 0);
    }
  }

  // epilogue: O /= l, write bf16 head-merged
  int orow0 = b * q_batch_rows + qt * 64 + wave * 16;
#pragma unroll
  for (int t = 0; t < 4; t++) {
#pragma unroll
    for (int r = 0; r < 4; r++) {
      float v = o_acc[t][r] / l_r[r];
      O[(size_t)(orow0 + quad * 4 + r) * o_rowstride + h * 64 + t * 16 + l15] = f2bf(v);
    }
  }
}

// ---------------------------------------------------------------------------
// Fused residual + LayerNorm over D=1024. 256 threads, 4 cols/thread.
// ---------------------------------------------------------------------------
__global__ __launch_bounds__(256)
void ln_kernel(const float* base, const float* __restrict__ delta,
               const float* __restrict__ g, const float* __restrict__ bb,
               float* outf, unsigned short* __restrict__ outb) {
  __shared__ float red[8];
  int row = blockIdx.x;
  int tid = threadIdx.x;
  float4 vb = ((const float4*)(base  + (size_t)row * 1024))[tid];
  float4 vd = ((const float4*)(delta + (size_t)row * 1024))[tid];
  float v0 = vb.x + vd.x, v1 = vb.y + vd.y, v2 = vb.z + vd.z, v3 = vb.w + vd.w;
  float s = v0 + v1 + v2 + v3;
  float q = v0 * v0 + v1 * v1 + v2 * v2 + v3 * v3;
#pragma unroll
  for (int d = 1; d < 64; d <<= 1) { s += __shfl_xor(s, d); q += __shfl_xor(q, d); }
  int wave = tid >> 6, lane = tid & 63;
  if (lane == 0) { red[wave] = s; red[4 + wave] = q; }
  __syncthreads();
  s = red[0] + red[1] + red[2] + red[3];
  q = red[4] + red[5] + red[6] + red[7];
  float mean = s * (1.f / 1024.f);
  float var  = q * (1.f / 1024.f) - mean * mean;
  float rstd = rsqrtf(var + 1e-5f);
  float4 gg  = ((const float4*)g)[tid];
  float4 bv  = ((const float4*)bb)[tid];
  float o0 = (v0 - mean) * rstd * gg.x + bv.x;
  float o1 = (v1 - mean) * rstd * gg.y + bv.y;
  float o2 = (v2 - mean) * rstd * gg.z + bv.z;
  float o3 = (v3 - mean) * rstd * gg.w + bv.w;
  if (outf) {
    float4 o; o.x = o0; o.y = o1; o.z = o2; o.w = o3;
    ((float4*)(outf + (size_t)row * 1024))[tid] = o;
  }
  if (outb) {
    ushort4 u; u.x = f2bf(o0); u.y = f2bf(o1); u.z = f2bf(o2); u.w = f2bf(o3);
    ((ushort4*)(outb + (size_t)row * 1024))[tid] = u;
  }
}

// ---------------------------------------------------------------------------
// Launch
// ---------------------------------------------------------------------------
extern "C" void kernel_launch(void* const* d_in, const int* in_sizes, int n_in,
                              void* d_out, int out_size, void* d_ws, size_t ws_size,
                              hipStream_t stream) {
  const float* x     = (const float*)d_in[0];
  const float* y     = (const float*)d_in[1];
  const float* w_qkv = (const float*)d_in[2];
  const float* b_qkv = (const float*)d_in[3];
  const float* w_so  = (const float*)d_in[4];
  const float* b_so  = (const float*)d_in[5];
  const float* w_q   = (const float*)d_in[6];
  const float* b_q   = (const float*)d_in[7];
  const float* w_k   = (const float*)d_in[8];
  const float* b_k   = (const float*)d_in[9];
  const float* w_v   = (const float*)d_in[10];
  const float* b_v   = (const float*)d_in[11];
  const float* w_co  = (const float*)d_in[12];
  const float* b_co  = (const float*)d_in[13];
  const float* w1    = (const float*)d_in[14];
  const float* b1    = (const float*)d_in[15];
  const float* w2    = (const float*)d_in[16];
  const float* b2    = (const float*)d_in[17];
  const float* w3    = (const float*)d_in[18];
  const float* b3    = (const float*)d_in[19];
  const float* ln_g  = (const float*)d_in[20];
  const float* ln_b  = (const float*)d_in[21];

  char* ws = (char*)d_ws;
  auto US = [&](size_t off) { return (unsigned short*)(ws + off); };
  auto FP = [&](size_t off) { return (float*)(ws + off); };

  // ws layout (bytes). Total ~168 MB.
  constexpr size_t o_wqkv = 0;                                 // [3072,1024] bf16
  constexpr size_t o_wso  = o_wqkv + 3072ull * 1024 * 2;       // [1024,1024]
  constexpr size_t o_wq   = o_wso  + 1024ull * 1024 * 2;
  constexpr size_t o_wk   = o_wq   + 1024ull * 1024 * 2;       // [1024,768]
  constexpr size_t o_wv   = o_wk   + 1024ull * 768 * 2;
  constexpr size_t o_wco  = o_wv   + 1024ull * 768 * 2;
  constexpr size_t o_w1   = o_wco  + 1024ull * 1024 * 2;       // [4096,1024]
  constexpr size_t o_w2   = o_w1   + 4096ull * 1024 * 2;       // [4096,4096]
  constexpr size_t o_w3   = o_w2   + 4096ull * 4096 * 2;       // [1024,4096]
  constexpr size_t o_xf   = o_w3   + 1024ull * 4096 * 2;       // x fp32 [4096,1024]
  constexpr size_t o_xbf  = o_xf   + 4096ull * 1024 * 4;       // x bf16
  constexpr size_t o_ybf  = o_xbf  + 4096ull * 1024 * 2;       // y bf16 [308,768]
  constexpr size_t o_dlt  = o_ybf  + 308ull * 768 * 2;         // delta fp32 [4096,1024]
  constexpr size_t o_R1   = o_dlt  + 4096ull * 1024 * 4;       // qkv bf16 [4096,3072]
  constexpr size_t o_attn = o_R1   + 4096ull * 3072 * 2;       // attn out bf16 [4096,1024]
  constexpr size_t o_R2   = o_attn + 4096ull * 1024 * 2;       // h2 bf16 [4096,4096]
  constexpr size_t o_qc = o_R1;
  constexpr size_t o_kc = o_R1 + 4096ull * 1024 * 2;
  constexpr size_t o_vc = o_kc + 308ull * 1024 * 2;
  constexpr size_t o_h1 = o_R1;
  constexpr size_t o_h2 = o_R2;

  dim3 tb(32, 8);
  // weight transpose-converts: in [K,N] fp32 -> out [N,K] bf16, grid (N/32,K/32)
  cvt_transpose<<<dim3(96, 32),  tb, 0, stream>>>(w_qkv, US(o_wqkv), 1024, 3072);
  cvt_transpose<<<dim3(32, 32),  tb, 0, stream>>>(w_so,  US(o_wso),  1024, 1024);
  cvt_transpose<<<dim3(32, 32),  tb, 0, stream>>>(w_q,   US(o_wq),   1024, 1024);
  cvt_transpose<<<dim3(32, 24),  tb, 0, stream>>>(w_k,   US(o_wk),   768,  1024);
  cvt_transpose<<<dim3(32, 24),  tb, 0, stream>>>(w_v,   US(o_wv),   768,  1024);
  cvt_transpose<<<dim3(32, 32),  tb, 0, stream>>>(w_co,  US(o_wco),  1024, 1024);
  cvt_transpose<<<dim3(128, 32), tb, 0, stream>>>(w1,    US(o_w1),   1024, 4096);
  cvt_transpose<<<dim3(128, 128),tb, 0, stream>>>(w2,    US(o_w2),   4096, 4096);
  cvt_transpose<<<dim3(32, 128), tb, 0, stream>>>(w3,    US(o_w3),   4096, 1024);

  cvt_f32_bf16<<<4096, 256, 0, stream>>>(x, US(o_xbf), 4096 * 1024 / 4);
  cvt_f32_bf16<<<231, 256, 0, stream>>>(y, US(o_ybf), 4 * 77 * 768 / 4);

  // --- self attention ---
  gemm_bf16<false, false, true><<<dim3(24, 32), 256, 0, stream>>>(
      US(o_xbf), US(o_wqkv), b_qkv, nullptr, US(o_R1), 4096, 3072, 1024);
  attn_kernel<<<dim3(16, 16, 4), 256, 0, stream>>>(
      US(o_R1), US(o_R1) + 1024, US(o_R1) + 2048, US(o_attn),
      3072, 3072, 1024, 1024, 1024, 1024, 0.125f);
  gemm_bf16<false, true, false><<<dim3(8, 32), 256, 0, stream>>>(
      US(o_attn), US(o_wso), b_so, FP(o_dlt), nullptr, 4096, 1024, 1024);
  ln_kernel<<<4096, 256, 0, stream>>>(x, FP(o_dlt), ln_g, ln_b, FP(o_xf), US(o_xbf));

  // --- cross attention ---
  gemm_bf16<false, false, true><<<dim3(8, 32), 256, 0, stream>>>(
      US(o_xbf), US(o_wq), b_q, nullptr, US(o_qc), 4096, 1024, 1024);
  gemm_bf16<false, false, true><<<dim3(8, 3), 256, 0, stream>>>(
      US(o_ybf), US(o_wk), b_k, nullptr, US(o_kc), 308, 1024, 768);
  gemm_bf16<false, false, true><<<dim3(8, 3), 256, 0, stream>>>(
      US(o_ybf), US(o_wv), b_v, nullptr, US(o_vc), 308, 1024, 768);
  attn_kernel<<<dim3(16, 16, 4), 256, 0, stream>>>(
      US(o_qc), US(o_kc), US(o_vc), US(o_attn),
      1024, 1024, 1024, 1024, 77, 77, 0.125f);
  gemm_bf16<false, true, false><<<dim3(8, 32), 256, 0, stream>>>(
      US(o_attn), US(o_wco), b_co, FP(o_dlt), nullptr, 4096, 1024, 1024);
  ln_kernel<<<4096, 256, 0, stream>>>(FP(o_xf), FP(o_dlt), ln_g, ln_b, FP(o_xf), US(o_xbf));

  // --- FFN ---
  gemm_bf16<true, false, true><<<dim3(32, 32), 256, 0, stream>>>(
      US(o_xbf), US(o_w1), b1, nullptr, US(o_h1), 4096, 4096, 1024);
  gemm_bf16<true, false, true><<<dim3(32, 32), 256, 0, stream>>>(
      US(o_h1), US(o_w2), b2, nullptr, US(o_h2), 4096, 4096, 4096);
  gemm_bf16<false, true, false><<<dim3(8, 32), 256, 0, stream>>>(
      US(o_h2), US(o_w3), b3, FP(o_dlt), nullptr, 4096, 1024, 4096);
  ln_kernel<<<4096, 256, 0, stream>>>(FP(o_xf), FP(o_dlt), ln_g, ln_b, (float*)d_out, nullptr);
}

// Round 3
// 837.477 us; speedup vs baseline: 1.1160x; 1.1133x over previous
//
#include <hip/hip_runtime.h>
#include <hip/hip_bf16.h>
#include <math.h>

// ---------------------------------------------------------------------------
// Types
// ---------------------------------------------------------------------------
typedef short v8s __attribute__((ext_vector_type(8)));   // 8 x bf16 bits (4 VGPR)
typedef float v4f __attribute__((ext_vector_type(4)));   // MFMA accumulator

__device__ __forceinline__ unsigned short f2bf(float f) {
  union { float f; unsigned u; } a; a.f = f;
  unsigned u = a.u + 0x7fffu + ((a.u >> 16) & 1u);   // RNE
  return (unsigned short)(u >> 16);
}

// async global->LDS, 16 B per lane; LDS dest = wave-uniform base + lane*16
__device__ __forceinline__ void gld_lds16(const unsigned short* g, unsigned short* l) {
  __builtin_amdgcn_global_load_lds(
      (const __attribute__((address_space(1))) void*)g,
      (__attribute__((address_space(3))) void*)l,
      16, 0, 0);
}

// ---------------------------------------------------------------------------
// fp32 -> bf16 (same layout), vectorized x4
// ---------------------------------------------------------------------------
__global__ void cvt_f32_bf16(const float* __restrict__ in,
                             unsigned short* __restrict__ out, int n4) {
  int i = blockIdx.x * blockDim.x + threadIdx.x;
  if (i >= n4) return;
  float4 v = reinterpret_cast<const float4*>(in)[i];
  ushort4 o;
  o.x = f2bf(v.x); o.y = f2bf(v.y); o.z = f2bf(v.z); o.w = f2bf(v.w);
  reinterpret_cast<ushort4*>(out)[i] = o;
}

// ---------------------------------------------------------------------------
// fp32 [K,N] -> bf16 [N,K] transpose-convert (weights). block (32,8)
// ---------------------------------------------------------------------------
__global__ void cvt_transpose(const float* __restrict__ in,
                              unsigned short* __restrict__ out, int K, int N) {
  __shared__ float t[32][33];
  int bx = blockIdx.x, by = blockIdx.y;
  int tx = threadIdx.x, ty = threadIdx.y;
#pragma unroll
  for (int i = 0; i < 4; i++) {
    int k = by * 32 + ty + i * 8;
    t[ty + i * 8][tx] = in[(size_t)k * N + bx * 32 + tx];
  }
  __syncthreads();
#pragma unroll
  for (int i = 0; i < 4; i++) {
    int n = bx * 32 + ty + i * 8;
    out[(size_t)n * K + by * 32 + tx] = f2bf(t[tx][ty + i * 8]);
  }
}

// ---------------------------------------------------------------------------
// bf16 MFMA GEMM: C[M,N] = act(A[M,K] @ B[K,N] + bias)
// A row-major bf16, BT = B^T row-major [N,K] bf16.
// 256 threads = 4 waves, tile 128x128, BK=64, each wave 64x64 (4x4 MFMA tiles).
// Staging via global_load_lds width=16 into lA/lB [128][64] (32 KB total).
// XOR swizzle: LDS chunk slot c holds global 16B-chunk (c ^ (row&7)) so the
// frag ds_read_b128s hit all 32 banks (conflict-free); the swizzle is realized
// by permuting the GLOBAL source address per lane (DMA lane->LDS map is fixed).
// Per K-step: 8 async issues/thread-equivalents, 2 barriers, 16 ds_read_b128,
// 32 MFMA per wave -> 2x matrix work per barrier-drain vs BK=32.
// Ragged M: OOB rows read workspace garbage (mapped) and are discarded at store.
// N must be mult of 128, K mult of 64.
// ---------------------------------------------------------------------------
template<bool RELU, bool OUTF, bool OUTB>
__global__ __launch_bounds__(256)
void gemm_bf16(const unsigned short* __restrict__ A,
               const unsigned short* __restrict__ BT,
               const float* __restrict__ bias,
               float* __restrict__ Cf, unsigned short* __restrict__ Cb,
               int M, int N, int K) {
  __shared__ __align__(16) unsigned short lA[128 * 64];   // 16 KB
  __shared__ __align__(16) unsigned short lB[128 * 64];
  int tid  = threadIdx.x;
  int lane = tid & 63;
  int wave = tid >> 6;
  int wr = (wave >> 1) * 64;
  int wc = (wave & 1) * 64;
  int quad = lane >> 4;
  int l15  = lane & 15;
  int m0 = blockIdx.y * 128;
  int n0 = blockIdx.x * 128;

  // staging map (per issue i, rows i*32..i*32+31):
  //   row = i*32 + (tid>>3), source chunk = (tid&7) ^ (row&7)  [swizzle]
  int srow   = tid >> 3;                       // 0..31
  int schunk = (tid & 7) ^ (srow & 7);
  const unsigned short* gA = A  + (size_t)(m0 + srow) * K + schunk * 8;
  const unsigned short* gB = BT + (size_t)(n0 + srow) * K + schunk * 8;
  unsigned short* ldsA = lA + wave * 512;      // wave-uniform byte base = wave*1024
  unsigned short* ldsB = lB + wave * 512;
  const size_t rowblk = (size_t)32 * K;        // 32 rows of global stride

  const v4f vzero = {0.f, 0.f, 0.f, 0.f};
  v4f acc[4][4];
#pragma unroll
  for (int i = 0; i < 4; i++)
#pragma unroll
    for (int j = 0; j < 4; j++) acc[i][j] = vzero;

  for (int k0 = 0; k0 < K; k0 += 64) {
#pragma unroll
    for (int i = 0; i < 4; i++) {
      gld_lds16(gA + k0 + i * rowblk, ldsA + i * 2048);
      gld_lds16(gB + k0 + i * rowblk, ldsB + i * 2048);
    }
    __syncthreads();                       // drains vmcnt -> LDS tile ready
#pragma unroll
    for (int s = 0; s < 2; s++) {
      v8s aF[4], bF[4];
#pragma unroll
      for (int i = 0; i < 4; i++)
        aF[i] = *(const v8s*)&lA[(wr + i * 16 + l15) * 64 + (((s * 4 + quad) ^ (l15 & 7)) * 8)];
#pragma unroll
      for (int j = 0; j < 4; j++)
        bF[j] = *(const v8s*)&lB[(wc + j * 16 + l15) * 64 + (((s * 4 + quad) ^ (l15 & 7)) * 8)];
#pragma unroll
      for (int i = 0; i < 4; i++)
#pragma unroll
        for (int j = 0; j < 4; j++)
          acc[i][j] = __builtin_amdgcn_mfma_f32_16x16x32_bf16(aF[i], bF[j], acc[i][j], 0, 0, 0);
    }
    __syncthreads();                       // frag reads done before next overwrite
  }

  // epilogue: C/D layout col=lane&15, row=quad*4+reg
#pragma unroll
  for (int j = 0; j < 4; j++) {
    int col = n0 + wc + j * 16 + l15;
    float bv = bias ? bias[col] : 0.f;
#pragma unroll
    for (int i = 0; i < 4; i++) {
#pragma unroll
      for (int r = 0; r < 4; r++) {
        int row = m0 + wr + i * 16 + quad * 4 + r;
        if (row < M) {
          float v = acc[i][j][r] + bv;
          if (RELU) v = fmaxf(v, 0.f);
          if (OUTF) Cf[(size_t)row * N + col] = v;
          if (OUTB) Cb[(size_t)row * N + col] = f2bf(v);
        }
      }
    }
  }
}

// ---------------------------------------------------------------------------
// Flash-style MFMA attention. grid (Sq/64, H, B), 256 threads = 4 waves.
// One WG: 64 query rows of one (b,h); KV chunks of 64, online softmax.
// Q/K/V bf16 with row stride; O bf16 [B*Sq, H*64] head-merged.
// ---------------------------------------------------------------------------
__global__ __launch_bounds__(256)
void attn_kernel(const unsigned short* __restrict__ Q,
                 const unsigned short* __restrict__ K,
                 const unsigned short* __restrict__ V,
                 unsigned short* __restrict__ O,
                 int q_rowstride, int kv_rowstride, int o_rowstride,
                 int q_batch_rows, int kv_batch_rows, int Skv, float scale) {
  __shared__ __align__(16) unsigned short lK[64][72];      // [kv][d]
  __shared__ __align__(16) unsigned short lV[64][72];      // transposed: [d][kv]
  __shared__ __align__(16) unsigned short lP[4][16][72];   // per-wave P (A-layout src)
  int tid  = threadIdx.x;
  int lane = tid & 63;
  int wave = tid >> 6;
  int quad = lane >> 4;
  int l15  = lane & 15;
  int qt = blockIdx.x, h = blockIdx.y, b = blockIdx.z;

  const unsigned short* Qb = Q + (size_t)b * q_batch_rows * q_rowstride + h * 64;
  const unsigned short* Kb = K + (size_t)b * kv_batch_rows * kv_rowstride + h * 64;
  const unsigned short* Vb = V + (size_t)b * kv_batch_rows * kv_rowstride + h * 64;

  // Q A-frags (rows qt*64 + wave*16 + l15, k = c*32 + quad*8 + j)
  v8s qf0, qf1;
  {
    const unsigned short* qr = Qb + (size_t)(qt * 64 + wave * 16 + l15) * q_rowstride + quad * 8;
    qf0 = *(const v8s*)(qr);
    qf1 = *(const v8s*)(qr + 32);
  }

  const v4f vzero = {0.f, 0.f, 0.f, 0.f};
  v4f o_acc[4];
#pragma unroll
  for (int t = 0; t < 4; t++) o_acc[t] = vzero;
  float m_r[4], l_r[4];
#pragma unroll
  for (int r = 0; r < 4; r++) { m_r[r] = -1e30f; l_r[r] = 0.f; }

  int sr = tid >> 2;            // kv row in chunk 0..63
  int sc = (tid & 3) * 16;      // 0/16/32/48

  int nch = (Skv + 63) >> 6;
  for (int ch = 0; ch < nch; ch++) {
    int base = ch * 64;
    int gr = base + sr;
    v8s k0v = {}, k1v = {}, v0v = {}, v1v = {};
    if (gr < Skv) {
      const unsigned short* kp = Kb + (size_t)gr * kv_rowstride + sc;
      const unsigned short* vp = Vb + (size_t)gr * kv_rowstride + sc;
      k0v = *(const v8s*)kp;  k1v = *(const v8s*)(kp + 8);
      v0v = *(const v8s*)vp;  v1v = *(const v8s*)(vp + 8);
    }
    __syncthreads();            // prev chunk's lV/lP reads done
    *(v8s*)&lK[sr][sc]     = k0v;
    *(v8s*)&lK[sr][sc + 8] = k1v;
#pragma unroll
    for (int e = 0; e < 8; e++) {
      lV[sc + e][sr]     = (unsigned short)v0v[e];
      lV[sc + 8 + e][sr] = (unsigned short)v1v[e];
    }
    __syncthreads();

    // S = Q K^T for 4 kv sub-tiles of 16
    float s[4][4];
#pragma unroll
    for (int t = 0; t < 4; t++) {
      v8s kf0 = *(const v8s*)&lK[t * 16 + l15][quad * 8];
      v8s kf1 = *(const v8s*)&lK[t * 16 + l15][32 + quad * 8];
      v4f sacc = vzero;
      sacc = __builtin_amdgcn_mfma_f32_16x16x32_bf16(qf0, kf0, sacc, 0, 0, 0);
      sacc = __builtin_amdgcn_mfma_f32_16x16x32_bf16(qf1, kf1, sacc, 0, 0, 0);
      int kvpos = base + t * 16 + l15;     // C-layout col = lane&15
      bool ok = kvpos < Skv;
#pragma unroll
      for (int r = 0; r < 4; r++) s[t][r] = ok ? sacc[r] * scale : -1e30f;
    }

    // online softmax per row (row r lives in the 16 lanes of this quad)
#pragma unroll
    for (int r = 0; r < 4; r++) {
      float mx = fmaxf(fmaxf(s[0][r], s[1][r]), fmaxf(s[2][r], s[3][r]));
#pragma unroll
      for (int d = 1; d < 16; d <<= 1) mx = fmaxf(mx, __shfl_xor(mx, d));
      float mnew = fmaxf(m_r[r], mx);
      float alpha = __expf(m_r[r] - mnew);
      float sm = 0.f;
#pragma unroll
      for (int t = 0; t < 4; t++) { s[t][r] = __expf(s[t][r] - mnew); sm += s[t][r]; }
#pragma unroll
      for (int d = 1; d < 16; d <<= 1) sm += __shfl_xor(sm, d);
      l_r[r] = l_r[r] * alpha + sm;
      m_r[r] = mnew;
#pragma unroll
      for (int t = 0; t < 4; t++) o_acc[t][r] *= alpha;
    }

    // P: C-layout -> LDS -> A-layout
#pragma unroll
    for (int t = 0; t < 4; t++)
#pragma unroll
      for (int r = 0; r < 4; r++)
        lP[wave][quad * 4 + r][t * 16 + l15] = f2bf(s[t][r]);
    __syncthreads();
    v8s pf0 = *(const v8s*)&lP[wave][l15][quad * 8];
    v8s pf1 = *(const v8s*)&lP[wave][l15][32 + quad * 8];
#pragma unroll
    for (int t = 0; t < 4; t++) {
      v8s vf0 = *(const v8s*)&lV[t * 16 + l15][quad * 8];
      v8s vf1 = *(const v8s*)&lV[t * 16 + l15][32 + quad * 8];
      o_acc[t] = __builtin_amdgcn_mfma_f32_16x16x32_bf16(pf0, vf0, o_acc[t], 0, 0, 0);
      o_acc[t] = __builtin_amdgcn_mfma_f32_16x16x32_bf16(pf1, vf1, o_acc[t], 0, 0, 0);
    }
  }

  // epilogue: O /= l, write bf16 head-merged
  int orow0 = b * q_batch_rows + qt * 64 + wave * 16;
#pragma unroll
  for (int t = 0; t < 4; t++) {
#pragma unroll
    for (int r = 0; r < 4; r++) {
      float v = o_acc[t][r] / l_r[r];
      O[(size_t)(orow0 + quad * 4 + r) * o_rowstride + h * 64 + t * 16 + l15] = f2bf(v);
    }
  }
}

// ---------------------------------------------------------------------------
// Fused residual + LayerNorm over D=1024. 256 threads, 4 cols/thread.
// ---------------------------------------------------------------------------
__global__ __launch_bounds__(256)
void ln_kernel(const float* base, const float* __restrict__ delta,
               const float* __restrict__ g, const float* __restrict__ bb,
               float* outf, unsigned short* __restrict__ outb) {
  __shared__ float red[8];
  int row = blockIdx.x;
  int tid = threadIdx.x;
  float4 vb = ((const float4*)(base  + (size_t)row * 1024))[tid];
  float4 vd = ((const float4*)(delta + (size_t)row * 1024))[tid];
  float v0 = vb.x + vd.x, v1 = vb.y + vd.y, v2 = vb.z + vd.z, v3 = vb.w + vd.w;
  float s = v0 + v1 + v2 + v3;
  float q = v0 * v0 + v1 * v1 + v2 * v2 + v3 * v3;
#pragma unroll
  for (int d = 1; d < 64; d <<= 1) { s += __shfl_xor(s, d); q += __shfl_xor(q, d); }
  int wave = tid >> 6, lane = tid & 63;
  if (lane == 0) { red[wave] = s; red[4 + wave] = q; }
  __syncthreads();
  s = red[0] + red[1] + red[2] + red[3];
  q = red[4] + red[5] + red[6] + red[7];
  float mean = s * (1.f / 1024.f);
  float var  = q * (1.f / 1024.f) - mean * mean;
  float rstd = rsqrtf(var + 1e-5f);
  float4 gg  = ((const float4*)g)[tid];
  float4 bv  = ((const float4*)bb)[tid];
  float o0 = (v0 - mean) * rstd * gg.x + bv.x;
  float o1 = (v1 - mean) * rstd * gg.y + bv.y;
  float o2 = (v2 - mean) * rstd * gg.z + bv.z;
  float o3 = (v3 - mean) * rstd * gg.w + bv.w;
  if (outf) {
    float4 o; o.x = o0; o.y = o1; o.z = o2; o.w = o3;
    ((float4*)(outf + (size_t)row * 1024))[tid] = o;
  }
  if (outb) {
    ushort4 u; u.x = f2bf(o0); u.y = f2bf(o1); u.z = f2bf(o2); u.w = f2bf(o3);
    ((ushort4*)(outb + (size_t)row * 1024))[tid] = u;
  }
}

// ---------------------------------------------------------------------------
// Launch
// ---------------------------------------------------------------------------
extern "C" void kernel_launch(void* const* d_in, const int* in_sizes, int n_in,
                              void* d_out, int out_size, void* d_ws, size_t ws_size,
                              hipStream_t stream) {
  const float* x     = (const float*)d_in[0];
  const float* y     = (const float*)d_in[1];
  const float* w_qkv = (const float*)d_in[2];
  const float* b_qkv = (const float*)d_in[3];
  const float* w_so  = (const float*)d_in[4];
  const float* b_so  = (const float*)d_in[5];
  const float* w_q   = (const float*)d_in[6];
  const float* b_q   = (const float*)d_in[7];
  const float* w_k   = (const float*)d_in[8];
  const float* b_k   = (const float*)d_in[9];
  const float* w_v   = (const float*)d_in[10];
  const float* b_v   = (const float*)d_in[11];
  const float* w_co  = (const float*)d_in[12];
  const float* b_co  = (const float*)d_in[13];
  const float* w1    = (const float*)d_in[14];
  const float* b1    = (const float*)d_in[15];
  const float* w2    = (const float*)d_in[16];
  const float* b2    = (const float*)d_in[17];
  const float* w3    = (const float*)d_in[18];
  const float* b3    = (const float*)d_in[19];
  const float* ln_g  = (const float*)d_in[20];
  const float* ln_b  = (const float*)d_in[21];

  char* ws = (char*)d_ws;
  auto US = [&](size_t off) { return (unsigned short*)(ws + off); };
  auto FP = [&](size_t off) { return (float*)(ws + off); };

  // ws layout (bytes). Total ~168 MB.
  constexpr size_t o_wqkv = 0;                                 // [3072,1024] bf16
  constexpr size_t o_wso  = o_wqkv + 3072ull * 1024 * 2;       // [1024,1024]
  constexpr size_t o_wq   = o_wso  + 1024ull * 1024 * 2;
  constexpr size_t o_wk   = o_wq   + 1024ull * 1024 * 2;       // [1024,768]
  constexpr size_t o_wv   = o_wk   + 1024ull * 768 * 2;
  constexpr size_t o_wco  = o_wv   + 1024ull * 768 * 2;
  constexpr size_t o_w1   = o_wco  + 1024ull * 1024 * 2;       // [4096,1024]
  constexpr size_t o_w2   = o_w1   + 4096ull * 1024 * 2;       // [4096,4096]
  constexpr size_t o_w3   = o_w2   + 4096ull * 4096 * 2;       // [1024,4096]
  constexpr size_t o_xf   = o_w3   + 1024ull * 4096 * 2;       // x fp32 [4096,1024]
  constexpr size_t o_xbf  = o_xf   + 4096ull * 1024 * 4;       // x bf16
  constexpr size_t o_ybf  = o_xbf  + 4096ull * 1024 * 2;       // y bf16 [308,768]
  constexpr size_t o_dlt  = o_ybf  + 308ull * 768 * 2;         // delta fp32 [4096,1024]
  constexpr size_t o_R1   = o_dlt  + 4096ull * 1024 * 4;       // qkv bf16 [4096,3072]
  constexpr size_t o_attn = o_R1   + 4096ull * 3072 * 2;       // attn out bf16 [4096,1024]
  constexpr size_t o_R2   = o_attn + 4096ull * 1024 * 2;       // h2 bf16 [4096,4096]
  constexpr size_t o_qc = o_R1;
  constexpr size_t o_kc = o_R1 + 4096ull * 1024 * 2;
  constexpr size_t o_vc = o_kc + 308ull * 1024 * 2;
  constexpr size_t o_h1 = o_R1;
  constexpr size_t o_h2 = o_R2;

  dim3 tb(32, 8);
  // weight transpose-converts: in [K,N] fp32 -> out [N,K] bf16, grid (N/32,K/32)
  cvt_transpose<<<dim3(96, 32),  tb, 0, stream>>>(w_qkv, US(o_wqkv), 1024, 3072);
  cvt_transpose<<<dim3(32, 32),  tb, 0, stream>>>(w_so,  US(o_wso),  1024, 1024);
  cvt_transpose<<<dim3(32, 32),  tb, 0, stream>>>(w_q,   US(o_wq),   1024, 1024);
  cvt_transpose<<<dim3(32, 24),  tb, 0, stream>>>(w_k,   US(o_wk),   768,  1024);
  cvt_transpose<<<dim3(32, 24),  tb, 0, stream>>>(w_v,   US(o_wv),   768,  1024);
  cvt_transpose<<<dim3(32, 32),  tb, 0, stream>>>(w_co,  US(o_wco),  1024, 1024);
  cvt_transpose<<<dim3(128, 32), tb, 0, stream>>>(w1,    US(o_w1),   1024, 4096);
  cvt_transpose<<<dim3(128, 128),tb, 0, stream>>>(w2,    US(o_w2),   4096, 4096);
  cvt_transpose<<<dim3(32, 128), tb, 0, stream>>>(w3,    US(o_w3),   4096, 1024);

  cvt_f32_bf16<<<4096, 256, 0, stream>>>(x, US(o_xbf), 4096 * 1024 / 4);
  cvt_f32_bf16<<<231, 256, 0, stream>>>(y, US(o_ybf), 4 * 77 * 768 / 4);

  // --- self attention ---
  gemm_bf16<false, false, true><<<dim3(24, 32), 256, 0, stream>>>(
      US(o_xbf), US(o_wqkv), b_qkv, nullptr, US(o_R1), 4096, 3072, 1024);
  attn_kernel<<<dim3(16, 16, 4), 256, 0, stream>>>(
      US(o_R1), US(o_R1) + 1024, US(o_R1) + 2048, US(o_attn),
      3072, 3072, 1024, 1024, 1024, 1024, 0.125f);
  gemm_bf16<false, true, false><<<dim3(8, 32), 256, 0, stream>>>(
      US(o_attn), US(o_wso), b_so, FP(o_dlt), nullptr, 4096, 1024, 1024);
  ln_kernel<<<4096, 256, 0, stream>>>(x, FP(o_dlt), ln_g, ln_b, FP(o_xf), US(o_xbf));

  // --- cross attention ---
  gemm_bf16<false, false, true><<<dim3(8, 32), 256, 0, stream>>>(
      US(o_xbf), US(o_wq), b_q, nullptr, US(o_qc), 4096, 1024, 1024);
  gemm_bf16<false, false, true><<<dim3(8, 3), 256, 0, stream>>>(
      US(o_ybf), US(o_wk), b_k, nullptr, US(o_kc), 308, 1024, 768);
  gemm_bf16<false, false, true><<<dim3(8, 3), 256, 0, stream>>>(
      US(o_ybf), US(o_wv), b_v, nullptr, US(o_vc), 308, 1024, 768);
  attn_kernel<<<dim3(16, 16, 4), 256, 0, stream>>>(
      US(o_qc), US(o_kc), US(o_vc), US(o_attn),
      1024, 1024, 1024, 1024, 77, 77, 0.125f);
  gemm_bf16<false, true, false><<<dim3(8, 32), 256, 0, stream>>>(
      US(o_attn), US(o_wco), b_co, FP(o_dlt), nullptr, 4096, 1024, 1024);
  ln_kernel<<<4096, 256, 0, stream>>>(FP(o_xf), FP(o_dlt), ln_g, ln_b, FP(o_xf), US(o_xbf));

  // --- FFN ---
  gemm_bf16<true, false, true><<<dim3(32, 32), 256, 0, stream>>>(
      US(o_xbf), US(o_w1), b1, nullptr, US(o_h1), 4096, 4096, 1024);
  gemm_bf16<true, false, true><<<dim3(32, 32), 256, 0, stream>>>(
      US(o_h1), US(o_w2), b2, nullptr, US(o_h2), 4096, 4096, 4096);
  gemm_bf16<false, true, false><<<dim3(8, 32), 256, 0, stream>>>(
      US(o_h2), US(o_w3), b3, FP(o_dlt), nullptr, 4096, 1024, 4096);
  ln_kernel<<<4096, 256, 0, stream>>>(FP(o_xf), FP(o_dlt), ln_g, ln_b, (float*)d_out, nullptr);
}